// Round 1
// baseline (318.070 us; speedup 1.0000x reference)
//
#include <hip/hip_runtime.h>
#include <hip/hip_bf16.h>
#include <cstdint>
#include <cstddef>

#define DIM   1024
#define NH    16
#define HD    64
#define BB    4
#define TT    2048

typedef __attribute__((ext_vector_type(8))) short bf16x8;
typedef __attribute__((ext_vector_type(4))) short bf16x4;
typedef __attribute__((ext_vector_type(4))) float f32x4;
typedef __attribute__((ext_vector_type(4))) unsigned short u16x4;
typedef unsigned short u16;

static __device__ __forceinline__ u16 f2bf(float f) {
  union { float f; unsigned u; } v; v.f = f;
  return (u16)((v.u + 0x7FFFu + ((v.u >> 16) & 1u)) >> 16);
}

// ---------------- elementwise f32 -> bf16 ----------------
__global__ __launch_bounds__(256) void k_cvt(const float* __restrict__ in,
                                             u16* __restrict__ out, int n4) {
  int i = blockIdx.x * 256 + threadIdx.x;
  if (i >= n4) return;
  float4 v = reinterpret_cast<const float4*>(in)[i];
  u16x4 o = { f2bf(v.x), f2bf(v.y), f2bf(v.z), f2bf(v.w) };
  *reinterpret_cast<u16x4*>(out + (size_t)i * 4) = o;
}

// ---------------- transpose f32[R][C] -> bf16[C][R] ----------------
__global__ __launch_bounds__(256) void k_transpose(const float* __restrict__ in,
                                                   u16* __restrict__ out,
                                                   int R, int C) {
  __shared__ float tile[32][33];
  int bx = blockIdx.x * 32;  // C dim
  int by = blockIdx.y * 32;  // R dim
  int tx = threadIdx.x & 31, ty = threadIdx.x >> 5;  // ty: 0..7
  #pragma unroll
  for (int i = 0; i < 32; i += 8)
    tile[ty + i][tx] = in[(size_t)(by + ty + i) * C + bx + tx];
  __syncthreads();
  #pragma unroll
  for (int i = 0; i < 32; i += 8)
    out[(size_t)(bx + ty + i) * R + by + tx] = f2bf(tile[tx][ty + i]);
}

// ---------------- GEMM: C[M][N] = A[M][K] * Bt[N][K]^T + bias ----------------
// 128x128 tile, BK=32, 4 waves (2x2), 16x16x32 bf16 MFMA, double-buffered LDS
// staged with global_load_lds width-16, 2-phase schedule.
template <int OUT_BF16>
__global__ __launch_bounds__(256, 2) void k_gemm(const u16* __restrict__ A,
                                                 const u16* __restrict__ Bt,
                                                 const float* __restrict__ bias,
                                                 u16* __restrict__ Cb,
                                                 float* __restrict__ Cf,
                                                 int M, int N, int K) {
  __shared__ __align__(16) u16 lA[2][128 * 32];
  __shared__ __align__(16) u16 lB[2][128 * 32];
  const int tid = threadIdx.x;
  const int m0 = blockIdx.y * 128, n0 = blockIdx.x * 128;
  const int lane = tid & 63;
  const int w = tid >> 6;
  const int g = lane >> 4, r = lane & 15;
  const int wm = w >> 1, wn = w & 1;

  f32x4 acc[4][4] = {};

  const int KT = K >> 5;

  auto stage = [&](int buf, int kt) {
    const int k0 = kt << 5;
    #pragma unroll
    for (int i = 0; i < 2; ++i) {
      int c = tid + 256 * i;
      int row = c >> 2, col = (c & 3) << 3;
      const u16* gp = A + (size_t)(m0 + row) * K + k0 + col;
      u16* lp = &lA[buf][c << 3];
      __builtin_amdgcn_global_load_lds((const __attribute__((address_space(1))) void*)gp,
                                       (__attribute__((address_space(3))) void*)lp, 16, 0, 0);
    }
    #pragma unroll
    for (int i = 0; i < 2; ++i) {
      int c = tid + 256 * i;
      int row = c >> 2, col = (c & 3) << 3;
      const u16* gp = Bt + (size_t)(n0 + row) * K + k0 + col;
      u16* lp = &lB[buf][c << 3];
      __builtin_amdgcn_global_load_lds((const __attribute__((address_space(1))) void*)gp,
                                       (__attribute__((address_space(3))) void*)lp, 16, 0, 0);
    }
  };

  stage(0, 0);
  asm volatile("s_waitcnt vmcnt(0)" ::: "memory");
  __syncthreads();

  int cur = 0;
  for (int kt = 0; kt < KT; ++kt) {
    if (kt + 1 < KT) stage(cur ^ 1, kt + 1);
    bf16x8 af[4], bfr[4];
    #pragma unroll
    for (int m = 0; m < 4; ++m)
      af[m] = *(const bf16x8*)&lA[cur][(wm * 64 + m * 16 + r) * 32 + g * 8];
    #pragma unroll
    for (int n = 0; n < 4; ++n)
      bfr[n] = *(const bf16x8*)&lB[cur][(wn * 64 + n * 16 + r) * 32 + g * 8];
    #pragma unroll
    for (int m = 0; m < 4; ++m)
      #pragma unroll
      for (int n = 0; n < 4; ++n)
        acc[m][n] = __builtin_amdgcn_mfma_f32_16x16x32_bf16(af[m], bfr[n], acc[m][n], 0, 0, 0);
    asm volatile("s_waitcnt vmcnt(0)" ::: "memory");
    __syncthreads();
    cur ^= 1;
  }

  // epilogue: C row = wm*64+m*16+g*4+reg, col = wn*64+n*16+r
  #pragma unroll
  for (int n = 0; n < 4; ++n) {
    int col = n0 + wn * 64 + n * 16 + r;
    float bv = bias[col];
    #pragma unroll
    for (int m = 0; m < 4; ++m) {
      #pragma unroll
      for (int reg = 0; reg < 4; ++reg) {
        int row = m0 + wm * 64 + m * 16 + g * 4 + reg;
        float val = acc[m][n][reg] + bv;
        if (OUT_BF16) Cb[(size_t)row * N + col] = f2bf(val);
        else          Cf[(size_t)row * N + col] = val;
      }
    }
  }
}

// ---------------- causal flash attention ----------------
// Grid: (B*NH)*32 blocks; each block = one (b,h) and 64 q-rows (4 waves x 16).
// Swapped QK^T: S^T = mfma(K, Q^T) so each lane's 8 S values belong to one
// q-row (col = lane&15). PV: O^T = mfma(V^T, P^T) with P^T direct from regs.
#define KVB 32
#define VTS 36  // padded V^T row stride (bf16 elems)

__global__ __launch_bounds__(256) void k_attn(const u16* __restrict__ qkv,
                                              u16* __restrict__ aout) {
  __shared__ __align__(16) u16 lK[KVB * 64];        // XOR-swizzled [32][64]
  __shared__ __align__(16) u16 lVt[64 * VTS];       // [d][key], padded
  __shared__ __align__(16) float lO[4][16][68];     // per-wave O staging

  const int bid = blockIdx.x;
  const int qt = 31 - (bid & 31);   // descending q-tiles first (load balance)
  const int bh = bid >> 5;
  const int b = bh >> 4, h = bh & 15;
  const int tid = threadIdx.x, w = tid >> 6, lane = tid & 63;
  const int g = lane >> 4, r = lane & 15;
  const int qbase = qt * 64;
  const int qglob = qbase + w * 16 + r;  // this lane's q row (as MFMA column)

  // Q fragments (B-operand layout): Q[qglob][d = kk*32 + g*8 + b]
  const u16* qp = qkv + (size_t)(b * TT + qglob) * (3 * DIM) + h * HD;
  bf16x8 qf[2];
  #pragma unroll
  for (int kk = 0; kk < 2; ++kk)
    qf[kk] = *(const bf16x8*)&qp[kk * 32 + g * 8];

  f32x4 o[4] = {};
  float mrow = -__builtin_inff(), lrow = 0.f;

  const int nkv = (qbase + 64) / KVB;  // causal extent for this block
  for (int kv = 0; kv < nkv; ++kv) {
    const int kv0 = kv * KVB;
    __syncthreads();
    {  // stage K (swizzled) and V^T (transposed, padded)
      int row = tid >> 3, c8 = tid & 7;
      const u16* gk = qkv + (size_t)(b * TT + kv0 + row) * (3 * DIM) + DIM + h * HD + c8 * 8;
      bf16x8 kvv = *(const bf16x8*)gk;
      int off = (row * 64 + c8 * 8) ^ ((row & 7) << 3);
      *(bf16x8*)&lK[off] = kvv;
      const u16* gv = qkv + (size_t)(b * TT + kv0 + row) * (3 * DIM) + 2 * DIM + h * HD + c8 * 8;
      bf16x8 vv = *(const bf16x8*)gv;
      #pragma unroll
      for (int j = 0; j < 8; ++j)
        lVt[(c8 * 8 + j) * VTS + row] = (u16)vv[j];
    }
    __syncthreads();

    // S^T = K * Q^T : A-frag = K[key = c*16 + r][d = kk*32 + g*8 + b]
    f32x4 s[2] = {};
    #pragma unroll
    for (int c = 0; c < 2; ++c) {
      #pragma unroll
      for (int kk = 0; kk < 2; ++kk) {
        int row = c * 16 + r;
        int off = (row * 64 + kk * 32 + g * 8) ^ ((row & 7) << 3);
        bf16x8 kf = *(const bf16x8*)&lK[off];
        s[c] = __builtin_amdgcn_mfma_f32_16x16x32_bf16(kf, qf[kk], s[c], 0, 0, 0);
      }
    }

    // mask + online softmax (key = kv0 + c*16 + g*4 + reg; all vals same q-row)
    float p[8];
    float tm = -__builtin_inff();
    #pragma unroll
    for (int c = 0; c < 2; ++c) {
      #pragma unroll
      for (int reg = 0; reg < 4; ++reg) {
        int key = kv0 + c * 16 + g * 4 + reg;
        float sv = s[c][reg] * 0.125f;
        sv = (key <= qglob) ? sv : -__builtin_inff();
        p[c * 4 + reg] = sv;
        tm = fmaxf(tm, sv);
      }
    }
    tm = fmaxf(tm, __shfl_xor(tm, 16));
    tm = fmaxf(tm, __shfl_xor(tm, 32));
    float mn = fmaxf(mrow, tm);
    bool any = (mn > -__builtin_inff());
    float corr = any ? __expf(mrow - mn) : 1.0f;
    float ps = 0.f;
    #pragma unroll
    for (int i = 0; i < 8; ++i) {
      float e = any ? __expf(p[i] - mn) : 0.0f;
      p[i] = e;
      ps += e;
    }
    ps += __shfl_xor(ps, 16);
    ps += __shfl_xor(ps, 32);
    lrow = lrow * corr + ps;
    mrow = mn;
    #pragma unroll
    for (int cd = 0; cd < 4; ++cd) o[cd] *= corr;

    // P^T B-frag: assumed k-map km(g,b) = b<4 ? 4g+b : 16+4g+(b-4) == reg order
    bf16x8 pf;
    #pragma unroll
    for (int i = 0; i < 8; ++i) pf[i] = (short)f2bf(p[i]);

    // O^T += V^T * P^T : A-frag = V^T[d = cd*16 + r][km(g,b)]
    #pragma unroll
    for (int cd = 0; cd < 4; ++cd) {
      const u16* vr = &lVt[(cd * 16 + r) * VTS];
      bf16x4 v0 = *(const bf16x4*)&vr[4 * g];
      bf16x4 v1 = *(const bf16x4*)&vr[16 + 4 * g];
      bf16x8 av;
      av[0] = v0[0]; av[1] = v0[1]; av[2] = v0[2]; av[3] = v0[3];
      av[4] = v1[0]; av[5] = v1[1]; av[6] = v1[2]; av[7] = v1[3];
      o[cd] = __builtin_amdgcn_mfma_f32_16x16x32_bf16(av, pf, o[cd], 0, 0, 0);
    }
  }

  // epilogue: normalize, transpose via LDS, coalesced bf16 stores
  float inv = 1.0f / lrow;
  #pragma unroll
  for (int cd = 0; cd < 4; ++cd)
    #pragma unroll
    for (int reg = 0; reg < 4; ++reg)
      lO[w][r][cd * 16 + g * 4 + reg] = o[cd][reg] * inv;
  __syncthreads();
  {
    int q = lane >> 2, ds = (lane & 3) * 16;
    int trow = qbase + w * 16 + q;
    u16 tmp[16];
    #pragma unroll
    for (int i = 0; i < 16; ++i) tmp[i] = f2bf(lO[w][q][ds + i]);
    u16* op = aout + (size_t)(b * TT + trow) * DIM + h * HD + ds;
    *(bf16x8*)&op[0] = *(const bf16x8*)&tmp[0];
    *(bf16x8*)&op[8] = *(const bf16x8*)&tmp[8];
  }
}

// ---------------- launcher ----------------
extern "C" void kernel_launch(void* const* d_in, const int* in_sizes, int n_in,
                              void* d_out, int out_size, void* d_ws, size_t ws_size,
                              hipStream_t stream) {
  const float* x    = (const float*)d_in[0];
  const float* Wqkv = (const float*)d_in[1];
  const float* bqkv = (const float*)d_in[2];
  const float* Wout = (const float*)d_in[3];
  const float* bout = (const float*)d_in[4];
  float* out = (float*)d_out;

  const int M = BB * TT;  // 8192
  u16* xb   = (u16*)d_ws;                      // [8192][1024]
  u16* wqt  = xb + (size_t)M * DIM;            // [3072][1024]
  u16* wot  = wqt + (size_t)3 * DIM * DIM;     // [1024][1024]
  u16* qkvb = wot + (size_t)DIM * DIM;         // [8192][3072]
  u16* aob  = qkvb + (size_t)M * 3 * DIM;      // [8192][1024]

  // conversions
  k_cvt<<<(M * DIM / 4 + 255) / 256, 256, 0, stream>>>(x, xb, M * DIM / 4);
  k_transpose<<<dim3(3 * DIM / 32, DIM / 32), 256, 0, stream>>>(Wqkv, wqt, DIM, 3 * DIM);
  k_transpose<<<dim3(DIM / 32, DIM / 32), 256, 0, stream>>>(Wout, wot, DIM, DIM);

  // qkv = x @ W_qkv + b_qkv  (bf16 out)
  k_gemm<1><<<dim3(3 * DIM / 128, M / 128), 256, 0, stream>>>(
      xb, wqt, bqkv, qkvb, nullptr, M, 3 * DIM, DIM);

  // attention
  k_attn<<<BB * NH * 32, 256, 0, stream>>>(qkvb, aob);

  // out = attn_out @ W_out + b_out  (f32 out)
  k_gemm<0><<<dim3(DIM / 128, M / 128), 256, 0, stream>>>(
      aob, wot, bout, nullptr, out, M, DIM, DIM);
}

// Round 2
// 216.058 us; speedup vs baseline: 1.4722x; 1.4722x over previous
//
#include <hip/hip_runtime.h>
#include <hip/hip_bf16.h>
#include <cstdint>
#include <cstddef>

#define DIM   1024
#define NH    16
#define HD    64
#define BB    4
#define TT    2048

typedef __attribute__((ext_vector_type(8))) short bf16x8;
typedef __attribute__((ext_vector_type(4))) short bf16x4;
typedef __attribute__((ext_vector_type(4))) float f32x4;
typedef __attribute__((ext_vector_type(4))) unsigned short u16x4;
typedef unsigned short u16;
typedef unsigned int u32;

#define NEG_INF (-__builtin_inff())
#define QSCALE 0.18033688011110543f  // 0.125 * log2(e): softmax becomes exp2

static __device__ __forceinline__ u16 f2bf(float f) {
  union { float f; unsigned u; } v; v.f = f;
  return (u16)((v.u + 0x7FFFu + ((v.u >> 16) & 1u)) >> 16);
}

static __device__ __forceinline__ float exp2_fast(float x) {
  float r;
  asm("v_exp_f32 %0, %1" : "=v"(r) : "v"(x));
  return r;
}

// ---------------- elementwise f32 -> bf16 ----------------
__global__ __launch_bounds__(256) void k_cvt(const float* __restrict__ in,
                                             u16* __restrict__ out, int n4) {
  int i = blockIdx.x * 256 + threadIdx.x;
  if (i >= n4) return;
  float4 v = reinterpret_cast<const float4*>(in)[i];
  u16x4 o = { f2bf(v.x), f2bf(v.y), f2bf(v.z), f2bf(v.w) };
  *reinterpret_cast<u16x4*>(out + (size_t)i * 4) = o;
}

// ---------------- transpose f32[R][C] -> bf16[C][R] ----------------
__global__ __launch_bounds__(256) void k_transpose(const float* __restrict__ in,
                                                   u16* __restrict__ out,
                                                   int R, int C) {
  __shared__ float tile[32][33];
  int bx = blockIdx.x * 32;  // C dim
  int by = blockIdx.y * 32;  // R dim
  int tx = threadIdx.x & 31, ty = threadIdx.x >> 5;  // ty: 0..7
  #pragma unroll
  for (int i = 0; i < 32; i += 8)
    tile[ty + i][tx] = in[(size_t)(by + ty + i) * C + bx + tx];
  __syncthreads();
  #pragma unroll
  for (int i = 0; i < 32; i += 8)
    out[(size_t)(bx + ty + i) * R + by + tx] = f2bf(tile[tx][ty + i]);
}

// ---------------- GEMM: C[M][N] = A[M][K] * Bt[N][K]^T + bias ----------------
// Optionally scales (val+bias) by `scale` for cols < scale_cols (Q pre-scale).
template <int OUT_BF16>
__global__ __launch_bounds__(256, 2) void k_gemm(const u16* __restrict__ A,
                                                 const u16* __restrict__ Bt,
                                                 const float* __restrict__ bias,
                                                 u16* __restrict__ Cb,
                                                 float* __restrict__ Cf,
                                                 int M, int N, int K,
                                                 int scale_cols, float scale) {
  __shared__ __align__(16) u16 lA[2][128 * 32];
  __shared__ __align__(16) u16 lB[2][128 * 32];
  const int tid = threadIdx.x;
  const int m0 = blockIdx.y * 128, n0 = blockIdx.x * 128;
  const int lane = tid & 63;
  const int w = tid >> 6;
  const int g = lane >> 4, r = lane & 15;
  const int wm = w >> 1, wn = w & 1;

  f32x4 acc[4][4] = {};

  const int KT = K >> 5;

  auto stage = [&](int buf, int kt) {
    const int k0 = kt << 5;
    #pragma unroll
    for (int i = 0; i < 2; ++i) {
      int c = tid + 256 * i;
      int row = c >> 2, col = (c & 3) << 3;
      const u16* gp = A + (size_t)(m0 + row) * K + k0 + col;
      u16* lp = &lA[buf][c << 3];
      __builtin_amdgcn_global_load_lds((const __attribute__((address_space(1))) void*)gp,
                                       (__attribute__((address_space(3))) void*)lp, 16, 0, 0);
    }
    #pragma unroll
    for (int i = 0; i < 2; ++i) {
      int c = tid + 256 * i;
      int row = c >> 2, col = (c & 3) << 3;
      const u16* gp = Bt + (size_t)(n0 + row) * K + k0 + col;
      u16* lp = &lB[buf][c << 3];
      __builtin_amdgcn_global_load_lds((const __attribute__((address_space(1))) void*)gp,
                                       (__attribute__((address_space(3))) void*)lp, 16, 0, 0);
    }
  };

  stage(0, 0);
  asm volatile("s_waitcnt vmcnt(0)" ::: "memory");
  __syncthreads();

  int cur = 0;
  for (int kt = 0; kt < KT; ++kt) {
    if (kt + 1 < KT) stage(cur ^ 1, kt + 1);
    bf16x8 af[4], bfr[4];
    #pragma unroll
    for (int m = 0; m < 4; ++m)
      af[m] = *(const bf16x8*)&lA[cur][(wm * 64 + m * 16 + r) * 32 + g * 8];
    #pragma unroll
    for (int n = 0; n < 4; ++n)
      bfr[n] = *(const bf16x8*)&lB[cur][(wn * 64 + n * 16 + r) * 32 + g * 8];
    #pragma unroll
    for (int m = 0; m < 4; ++m)
      #pragma unroll
      for (int n = 0; n < 4; ++n)
        acc[m][n] = __builtin_amdgcn_mfma_f32_16x16x32_bf16(af[m], bfr[n], acc[m][n], 0, 0, 0);
    asm volatile("s_waitcnt vmcnt(0)" ::: "memory");
    __syncthreads();
    cur ^= 1;
  }

  // epilogue: C row = wm*64+m*16+g*4+reg, col = wn*64+n*16+r
  #pragma unroll
  for (int n = 0; n < 4; ++n) {
    int col = n0 + wn * 64 + n * 16 + r;
    float bv = bias[col];
    float sc = (col < scale_cols) ? scale : 1.0f;
    #pragma unroll
    for (int m = 0; m < 4; ++m) {
      #pragma unroll
      for (int reg = 0; reg < 4; ++reg) {
        int row = m0 + wm * 64 + m * 16 + g * 4 + reg;
        float val = (acc[m][n][reg] + bv) * sc;
        if (OUT_BF16) Cb[(size_t)row * N + col] = f2bf(val);
        else          Cf[(size_t)row * N + col] = val;
      }
    }
  }
}

// ---------------- causal flash attention ----------------
// Block = 4 waves, QBLK=128 (2 q-blocks of 64, wave owns rows qb*64+w*16+r),
// KVB=64. Swapped QK^T (lane owns one q-row per qb). K staged via
// global_load_lds with pre-swizzled global source (linear LDS dest, XOR read).
// V staged global->reg (1 tile ahead) -> packed u32 transpose writes (T14).
// One barrier per tile. Masking only on the 2 diagonal tiles; qb0 skipped on
// the last tile (its rows are entirely above the diagonal there).
#define KVB 64
#define VTS 76                       // V^T row stride: read banks = 6r+2g (min-phase)
#define LBUF (8192 + 64 * VTS * 2)   // K tile + V^T tile per buffer

__global__ __launch_bounds__(256, 2) void k_attn(const u16* __restrict__ qkv,
                                                 u16* __restrict__ aout) {
  __shared__ __align__(16) unsigned char smem[2 * LBUF];

  const int bid = blockIdx.x;
  const int swz = (bid & 7) * 128 + (bid >> 3);   // XCD swizzle (1024 % 8 == 0)
  const int bh = swz >> 4;
  const int qt = 15 - (swz & 15);                 // big q-tiles dispatched first
  const int b = bh >> 4, h = bh & 15;
  const int tid = threadIdx.x, w = tid >> 6, lane = tid & 63;
  const int g = lane >> 4, r = lane & 15;
  const int qbase = qt * 128;
  const int qg0 = qbase + w * 16 + r;             // qb0 row; qb1 row = qg0+64

  // Q fragments (B-operand): Q[q-row][d = kk*32 + g*8 + i] (scale pre-folded)
  bf16x8 qf[2][2];
  #pragma unroll
  for (int qb = 0; qb < 2; ++qb) {
    const u16* qp = qkv + ((size_t)(b * TT) + qg0 + qb * 64) * (3 * DIM) + h * HD;
    #pragma unroll
    for (int kk = 0; kk < 2; ++kk)
      qf[qb][kk] = *(const bf16x8*)&qp[kk * 32 + g * 8];
  }

  f32x4 o[2][4] = {};
  float mrow[2] = { NEG_INF, NEG_INF };
  float lrow[2] = { 0.f, 0.f };

  const int nt = 2 * qt + 2;

  auto lK = [&](int buf) -> u16* { return (u16*)(smem + (size_t)buf * LBUF); };
  auto lV = [&](int buf) -> u16* { return (u16*)(smem + (size_t)buf * LBUF + 8192); };

  auto issueK = [&](int buf, int t) {
    const int kv0 = t * KVB;
    u16* base = lK(buf);
    #pragma unroll
    for (int i = 0; i < 2; ++i) {
      int s = tid + 256 * i;
      int row = s >> 3, c8s = s & 7;
      int colg = c8s ^ (row & 7);   // pre-swizzled source, linear LDS dest
      const u16* gp = qkv + ((size_t)(b * TT) + kv0 + row) * (3 * DIM) + DIM + h * HD + colg * 8;
      __builtin_amdgcn_global_load_lds(
          (const __attribute__((address_space(1))) void*)gp,
          (__attribute__((address_space(3))) void*)(base + (size_t)s * 8), 16, 0, 0);
    }
  };

  const int vrg = tid >> 3, vc8 = tid & 7;  // V: rows 2vrg,2vrg+1, cols vc8*8
  auto loadV = [&](int t, bf16x8& a, bf16x8& c) {
    const int kv0 = t * KVB;
    const u16* gp = qkv + ((size_t)(b * TT) + kv0 + 2 * vrg) * (3 * DIM) + 2 * DIM + h * HD + vc8 * 8;
    a = *(const bf16x8*)gp;
    c = *(const bf16x8*)(gp + 3 * DIM);
  };
  auto writeV = [&](int buf, const bf16x8& a, const bf16x8& c) {
    u16* base = lV(buf);
    #pragma unroll
    for (int j = 0; j < 8; ++j) {
      u32 val = (u32)(u16)a[j] | ((u32)(u16)c[j] << 16);  // keys 2vrg, 2vrg+1
      *(u32*)&base[(vc8 * 8 + j) * VTS + 2 * vrg] = val;
    }
  };

  // prologue: tile 0 fully staged, tile 1 in flight
  bf16x8 sv0, sv1;
  issueK(0, 0);
  loadV(0, sv0, sv1);
  writeV(0, sv0, sv1);
  issueK(1, 1);
  loadV(1, sv0, sv1);
  __syncthreads();   // drains vmcnt(0): K(0) in LDS, K(1)/V(1) may also land early

  int cur = 0;
  for (int t = 0; t < nt; ++t) {
    const bool last = (t == nt - 1);
    const bool pen  = (t == nt - 2);
    const bool do0  = !last;   // last tile: qb0 rows entirely masked -> skip
    const bool m0   = pen;     // qb0 diagonal tile
    const bool m1   = last;    // qb1 diagonal tile
    const int kv0 = t * KVB;
    const u16* lk = lK(cur);
    const u16* lv = lV(cur);

    // ---- QK^T (K-frags shared across qb) ----
    f32x4 s0[4] = {}, s1[4] = {};
    #pragma unroll
    for (int c = 0; c < 4; ++c) {
      const int row = c * 16 + r;
      const int sw = (r & 7) << 3;
      bf16x8 kf0 = *(const bf16x8*)&lk[(row * 64 + g * 8) ^ sw];
      bf16x8 kf1 = *(const bf16x8*)&lk[(row * 64 + 32 + g * 8) ^ sw];
      if (do0) {
        s0[c] = __builtin_amdgcn_mfma_f32_16x16x32_bf16(kf0, qf[0][0], s0[c], 0, 0, 0);
        s0[c] = __builtin_amdgcn_mfma_f32_16x16x32_bf16(kf1, qf[0][1], s0[c], 0, 0, 0);
      }
      s1[c] = __builtin_amdgcn_mfma_f32_16x16x32_bf16(kf0, qf[1][0], s1[c], 0, 0, 0);
      s1[c] = __builtin_amdgcn_mfma_f32_16x16x32_bf16(kf1, qf[1][1], s1[c], 0, 0, 0);
    }

    // ---- online softmax per q-block (values already in log2 units) ----
    bf16x8 pf0[2], pf1[2];
    auto softmax = [&](f32x4* s, float& mref, float& lref, f32x4* ov,
                       bf16x8* pf, bool msk, int qg) {
      float pv[16];
      #pragma unroll
      for (int c = 0; c < 4; ++c)
        #pragma unroll
        for (int e = 0; e < 4; ++e) {
          float sv = s[c][e];
          if (msk) {
            int key = kv0 + c * 16 + g * 4 + e;
            if (key > qg) sv = NEG_INF;
          }
          pv[c * 4 + e] = sv;
        }
      float t8[8];
      #pragma unroll
      for (int i = 0; i < 8; ++i) t8[i] = fmaxf(pv[i], pv[i + 8]);
      #pragma unroll
      for (int i = 0; i < 4; ++i) t8[i] = fmaxf(t8[i], t8[i + 4]);
      float tm = fmaxf(fmaxf(t8[0], t8[1]), fmaxf(t8[2], t8[3]));
      tm = fmaxf(tm, __shfl_xor(tm, 16));
      tm = fmaxf(tm, __shfl_xor(tm, 32));
      const float mn = fmaxf(mref, tm);
      const float corr = exp2_fast(mref - mn);  // mref=-inf -> 0 (first tile)
      #pragma unroll
      for (int i = 0; i < 16; ++i) pv[i] = exp2_fast(pv[i] - mn);
      float a8[8];
      #pragma unroll
      for (int i = 0; i < 8; ++i) a8[i] = pv[i] + pv[i + 8];
      #pragma unroll
      for (int i = 0; i < 4; ++i) a8[i] = a8[i] + a8[i + 4];
      float ps = (a8[0] + a8[1]) + (a8[2] + a8[3]);
      ps += __shfl_xor(ps, 16);
      ps += __shfl_xor(ps, 32);
      lref = lref * corr + ps;
      mref = mn;
      #pragma unroll
      for (int cd = 0; cd < 4; ++cd) ov[cd] *= corr;
      #pragma unroll
      for (int hh = 0; hh < 2; ++hh)
        #pragma unroll
        for (int i = 0; i < 8; ++i) pf[hh][i] = (short)f2bf(pv[hh * 8 + i]);
    };
    if (do0) softmax(s0, mrow[0], lrow[0], o[0], pf0, m0, qg0);
    softmax(s1, mrow[1], lrow[1], o[1], pf1, m1, qg0 + 64);

    // ---- PV: O^T += V^T * P^T (V-frags shared across qb) ----
    #pragma unroll
    for (int cd = 0; cd < 4; ++cd) {
      const u16* vr = &lv[(cd * 16 + r) * VTS];
      #pragma unroll
      for (int ks = 0; ks < 2; ++ks) {
        bf16x4 a0 = *(const bf16x4*)&vr[ks * 32 + 4 * g];
        bf16x4 a1 = *(const bf16x4*)&vr[ks * 32 + 16 + 4 * g];
        bf16x8 av = { a0[0], a0[1], a0[2], a0[3], a1[0], a1[1], a1[2], a1[3] };
        if (do0) o[0][cd] = __builtin_amdgcn_mfma_f32_16x16x32_bf16(av, pf0[ks], o[0][cd], 0, 0, 0);
        o[1][cd] = __builtin_amdgcn_mfma_f32_16x16x32_bf16(av, pf1[ks], o[1][cd], 0, 0, 0);
      }
    }

    // ---- T14 write-late: V(t+1) regs -> LDS buf^1 ----
    if (!last) writeV(cur ^ 1, sv0, sv1);
    __syncthreads();
    // ---- issue-early for t+2 (buf cur is free now) ----
    if (t + 2 < nt) { issueK(cur, t + 2); loadV(t + 2, sv0, sv1); }
    cur ^= 1;
  }

  // ---- epilogue: normalize, transpose via LDS (reused), coalesced stores ----
  float* lo = (float*)smem;  // [4 waves][32 rows][65]
  const float inv0 = 1.0f / lrow[0], inv1 = 1.0f / lrow[1];
  #pragma unroll
  for (int qb = 0; qb < 2; ++qb) {
    const float iv = qb ? inv1 : inv0;
    #pragma unroll
    for (int cd = 0; cd < 4; ++cd)
      #pragma unroll
      for (int e = 0; e < 4; ++e)
        lo[(w * 32 + qb * 16 + r) * 65 + cd * 16 + g * 4 + e] = o[qb][cd][e] * iv;
  }
  __syncthreads();
  {
    const int rowidx = lane >> 1, half = lane & 1;
    const int qb2 = rowidx >> 4, q = rowidx & 15;
    const int grow = qbase + qb2 * 64 + w * 16 + q;
    const float* src = &lo[(w * 32 + rowidx) * 65 + half * 32];
    u16 tmp[32];
    #pragma unroll
    for (int i = 0; i < 32; ++i) tmp[i] = f2bf(src[i]);
    u16* op = aout + ((size_t)(b * TT) + grow) * DIM + h * HD + half * 32;
    #pragma unroll
    for (int i = 0; i < 4; ++i)
      *(bf16x8*)&op[i * 8] = *(const bf16x8*)&tmp[i * 8];
  }
}

// ---------------- launcher ----------------
extern "C" void kernel_launch(void* const* d_in, const int* in_sizes, int n_in,
                              void* d_out, int out_size, void* d_ws, size_t ws_size,
                              hipStream_t stream) {
  const float* x    = (const float*)d_in[0];
  const float* Wqkv = (const float*)d_in[1];
  const float* bqkv = (const float*)d_in[2];
  const float* Wout = (const float*)d_in[3];
  const float* bout = (const float*)d_in[4];
  float* out = (float*)d_out;

  const int M = BB * TT;  // 8192
  u16* xb   = (u16*)d_ws;                      // [8192][1024]
  u16* wqt  = xb + (size_t)M * DIM;            // [3072][1024]
  u16* wot  = wqt + (size_t)3 * DIM * DIM;     // [1024][1024]
  u16* qkvb = wot + (size_t)DIM * DIM;         // [8192][3072]
  u16* aob  = qkvb + (size_t)M * 3 * DIM;      // [8192][1024]

  // conversions
  k_cvt<<<(M * DIM / 4 + 255) / 256, 256, 0, stream>>>(x, xb, M * DIM / 4);
  k_transpose<<<dim3(3 * DIM / 32, DIM / 32), 256, 0, stream>>>(Wqkv, wqt, DIM, 3 * DIM);
  k_transpose<<<dim3(DIM / 32, DIM / 32), 256, 0, stream>>>(Wout, wot, DIM, DIM);

  // qkv = x @ W_qkv + b_qkv  (bf16 out; Q columns pre-scaled by 0.125*log2e)
  k_gemm<1><<<dim3(3 * DIM / 128, M / 128), 256, 0, stream>>>(
      xb, wqt, bqkv, qkvb, nullptr, M, 3 * DIM, DIM, DIM, QSCALE);

  // attention
  k_attn<<<BB * NH * 16, 256, 0, stream>>>(qkvb, aob);

  // out = attn_out @ W_out + b_out  (f32 out)
  k_gemm<0><<<dim3(DIM / 128, M / 128), 256, 0, stream>>>(
      aob, wot, bout, nullptr, out, M, DIM, DIM, 0, 1.0f);
}

// Round 3
// 178.865 us; speedup vs baseline: 1.7783x; 1.2079x over previous
//
#include <hip/hip_runtime.h>
#include <hip/hip_bf16.h>
#include <cstdint>
#include <cstddef>

#define DIM   1024
#define NH    16
#define HD    64
#define BB    4
#define TT    2048

typedef __attribute__((ext_vector_type(8))) short bf16x8;
typedef __attribute__((ext_vector_type(4))) short bf16x4;
typedef __attribute__((ext_vector_type(4))) float f32x4;
typedef __attribute__((ext_vector_type(4))) unsigned short u16x4;
typedef unsigned short u16;
typedef unsigned int u32;

#define NEG_INF (-__builtin_inff())
#define QSCALE 0.18033688011110543f  // 0.125 * log2(e): softmax becomes exp2
#define AS1 __attribute__((address_space(1)))
#define AS3 __attribute__((address_space(3)))

static __device__ __forceinline__ u16 f2bf(float f) {
  union { float f; unsigned u; } v; v.f = f;
  return (u16)((v.u + 0x7FFFu + ((v.u >> 16) & 1u)) >> 16);
}

static __device__ __forceinline__ u16 bfbits(float a) {
  union { __hip_bfloat16 h; u16 u; } c; c.h = __float2bfloat16(a); return c.u;
}
static __device__ __forceinline__ u32 pk_bf16(float a, float b) {
  return (u32)bfbits(a) | ((u32)bfbits(b) << 16);
}

static __device__ __forceinline__ float exp2_fast(float x) {
  float r;
  asm("v_exp_f32 %0, %1" : "=v"(r) : "v"(x));
  return r;
}

// HW transpose read: lane l receives column (l&15) of the 4x16 bf16 tile at
// (addr - lane*8 + (l>>4)*128); callers pass addr = base + lane*8.
static __device__ __forceinline__ bf16x4 tr16(u32 byte_addr) {
  bf16x4 d;
  asm volatile("ds_read_b64_tr_b16 %0, %1" : "=v"(d) : "v"(byte_addr));
  return d;
}

// ---------------- elementwise f32 -> bf16 ----------------
__global__ __launch_bounds__(256) void k_cvt(const float* __restrict__ in,
                                             u16* __restrict__ out, int n4) {
  int i = blockIdx.x * 256 + threadIdx.x;
  if (i >= n4) return;
  float4 v = reinterpret_cast<const float4*>(in)[i];
  u16x4 o = { f2bf(v.x), f2bf(v.y), f2bf(v.z), f2bf(v.w) };
  *reinterpret_cast<u16x4*>(out + (size_t)i * 4) = o;
}

// ---------------- transpose f32[R][C] -> bf16[C][R] ----------------
__global__ __launch_bounds__(256) void k_transpose(const float* __restrict__ in,
                                                   u16* __restrict__ out,
                                                   int R, int C) {
  __shared__ float tile[32][33];
  int bx = blockIdx.x * 32;  // C dim
  int by = blockIdx.y * 32;  // R dim
  int tx = threadIdx.x & 31, ty = threadIdx.x >> 5;  // ty: 0..7
  #pragma unroll
  for (int i = 0; i < 32; i += 8)
    tile[ty + i][tx] = in[(size_t)(by + ty + i) * C + bx + tx];
  __syncthreads();
  #pragma unroll
  for (int i = 0; i < 32; i += 8)
    out[(size_t)(bx + ty + i) * R + by + tx] = f2bf(tile[tx][ty + i]);
}

// ---------------- GEMM: C[M][N] = A[M][K] * Bt[N][K]^T + bias ----------------
template <int OUT_BF16>
__global__ __launch_bounds__(256, 2) void k_gemm(const u16* __restrict__ A,
                                                 const u16* __restrict__ Bt,
                                                 const float* __restrict__ bias,
                                                 u16* __restrict__ Cb,
                                                 float* __restrict__ Cf,
                                                 int M, int N, int K,
                                                 int scale_cols, float scale) {
  __shared__ __align__(16) u16 lA[2][128 * 32];
  __shared__ __align__(16) u16 lB[2][128 * 32];
  const int tid = threadIdx.x;
  const int m0 = blockIdx.y * 128, n0 = blockIdx.x * 128;
  const int lane = tid & 63;
  const int w = tid >> 6;
  const int g = lane >> 4, r = lane & 15;
  const int wm = w >> 1, wn = w & 1;

  f32x4 acc[4][4] = {};

  const int KT = K >> 5;

  auto stage = [&](int buf, int kt) {
    const int k0 = kt << 5;
    #pragma unroll
    for (int i = 0; i < 2; ++i) {
      int c = tid + 256 * i;
      int row = c >> 2, col = (c & 3) << 3;
      const u16* gp = A + (size_t)(m0 + row) * K + k0 + col;
      u16* lp = &lA[buf][c << 3];
      __builtin_amdgcn_global_load_lds((const AS1 void*)gp, (AS3 void*)lp, 16, 0, 0);
    }
    #pragma unroll
    for (int i = 0; i < 2; ++i) {
      int c = tid + 256 * i;
      int row = c >> 2, col = (c & 3) << 3;
      const u16* gp = Bt + (size_t)(n0 + row) * K + k0 + col;
      u16* lp = &lB[buf][c << 3];
      __builtin_amdgcn_global_load_lds((const AS1 void*)gp, (AS3 void*)lp, 16, 0, 0);
    }
  };

  stage(0, 0);
  asm volatile("s_waitcnt vmcnt(0)" ::: "memory");
  __syncthreads();

  int cur = 0;
  for (int kt = 0; kt < KT; ++kt) {
    if (kt + 1 < KT) stage(cur ^ 1, kt + 1);
    bf16x8 af[4], bfr[4];
    #pragma unroll
    for (int m = 0; m < 4; ++m)
      af[m] = *(const bf16x8*)&lA[cur][(wm * 64 + m * 16 + r) * 32 + g * 8];
    #pragma unroll
    for (int n = 0; n < 4; ++n)
      bfr[n] = *(const bf16x8*)&lB[cur][(wn * 64 + n * 16 + r) * 32 + g * 8];
    #pragma unroll
    for (int m = 0; m < 4; ++m)
      #pragma unroll
      for (int n = 0; n < 4; ++n)
        acc[m][n] = __builtin_amdgcn_mfma_f32_16x16x32_bf16(af[m], bfr[n], acc[m][n], 0, 0, 0);
    asm volatile("s_waitcnt vmcnt(0)" ::: "memory");
    __syncthreads();
    cur ^= 1;
  }

  #pragma unroll
  for (int n = 0; n < 4; ++n) {
    int col = n0 + wn * 64 + n * 16 + r;
    float bv = bias[col];
    float sc = (col < scale_cols) ? scale : 1.0f;
    #pragma unroll
    for (int m = 0; m < 4; ++m) {
      #pragma unroll
      for (int reg = 0; reg < 4; ++reg) {
        int row = m0 + wm * 64 + m * 16 + g * 4 + reg;
        float val = (acc[m][n][reg] + bv) * sc;
        if (OUT_BF16) Cb[(size_t)row * N + col] = f2bf(val);
        else          Cf[(size_t)row * N + col] = val;
      }
    }
  }
}

// ---------------- causal flash attention ----------------
// 512 blocks; block = (b,h) x q-tile-pair {15-p, p} (uniform 34 tiles/block).
// Per half: QBLK=128 (2 q-blocks of 64), KVB=64, 4 waves. Swapped QK^T.
// K: global_load_lds, pre-swizzled source + XOR b128 reads.
// V: global_load_lds into [dblk=4][key=64][dcol=16] subtiles, read with
// ds_read_b64_tr_b16 (HW transpose) directly as PV A-fragments.
#define KVB 64
#define LBUF16 8192   // u16 elems per buffer: K 4096 + V 4096

__global__ __launch_bounds__(256, 2) void k_attn(const u16* __restrict__ qkv,
                                                 u16* __restrict__ aout) {
  __shared__ __align__(16) u16 smem[2 * LBUF16];

  const int bid = blockIdx.x;
  const int swz = (bid & 7) * 64 + (bid >> 3);   // XCD swizzle (512 % 8 == 0)
  const int bh = swz >> 3;
  const int p = swz & 7;
  const int b = bh >> 4, h = bh & 15;
  const int tid = threadIdx.x, w = tid >> 6, lane = tid & 63;
  const int g = lane >> 4, r = lane & 15;

  const u32 vls0 = (u32)(uintptr_t)(AS3 u16*)(smem + 4096);
  const u32 vls1 = (u32)(uintptr_t)(AS3 u16*)(smem + LBUF16 + 4096);

  auto issueKV = [&](int buf, int t) {
    const int kv0 = t * KVB;
    u16* kb = &smem[buf * LBUF16];
    u16* vb = &smem[buf * LBUF16 + 4096];
    #pragma unroll
    for (int i = 0; i < 2; ++i) {
      int s = tid + 256 * i;
      int row = s >> 3, c8 = s & 7;
      int colg = c8 ^ (row & 7);   // pre-swizzled source, linear LDS dest
      const u16* gp = qkv + ((size_t)(b * TT) + kv0 + row) * (3 * DIM) + DIM + h * HD + colg * 8;
      __builtin_amdgcn_global_load_lds((const AS1 void*)gp,
                                       (AS3 void*)(kb + (size_t)s * 8), 16, 0, 0);
    }
    #pragma unroll
    for (int i = 0; i < 2; ++i) {
      int s = tid + 256 * i;
      int key = (s >> 1) & 63;
      int c = ((s >> 7) << 1) | (s & 1);
      const u16* gp = qkv + ((size_t)(b * TT) + kv0 + key) * (3 * DIM) + 2 * DIM + h * HD + c * 8;
      __builtin_amdgcn_global_load_lds((const AS1 void*)gp,
                                       (AS3 void*)(vb + (size_t)s * 8), 16, 0, 0);
    }
  };

  for (int half = 0; half < 2; ++half) {
    const int qt = half ? p : (15 - p);
    const int qbase = qt * 128;
    const int nt = 2 * qt + 2;
    const int qg0 = qbase + w * 16 + r;

    // Q fragments (B-operand): Q[q-row][d = kk*32 + g*8 + i] (scale pre-folded)
    bf16x8 qf[2][2];
    #pragma unroll
    for (int qb = 0; qb < 2; ++qb) {
      const u16* qp = qkv + ((size_t)(b * TT) + qg0 + qb * 64) * (3 * DIM) + h * HD;
      #pragma unroll
      for (int kk = 0; kk < 2; ++kk)
        qf[qb][kk] = *(const bf16x8*)&qp[kk * 32 + g * 8];
    }

    f32x4 o[2][4] = {};
    float mrow[2] = { NEG_INF, NEG_INF };
    float lrow[2] = { 0.f, 0.f };

    issueKV(0, 0);
    issueKV(1, 1);
    __syncthreads();

    int cur = 0;
    for (int t = 0; t < nt; ++t) {
      const bool last = (t == nt - 1);
      const bool pen  = (t == nt - 2);
      const bool do0  = !last;
      const int kv0 = t * KVB;
      const u16* lk = &smem[cur * LBUF16];

      // ---- QK^T (K-frags shared across qb) ----
      f32x4 s0[4] = {}, s1[4] = {};
      __builtin_amdgcn_s_setprio(1);
      #pragma unroll
      for (int c = 0; c < 4; ++c) {
        const int row = c * 16 + r;
        const int sw = (r & 7) << 3;
        bf16x8 kf0 = *(const bf16x8*)&lk[(row * 64 + g * 8) ^ sw];
        bf16x8 kf1 = *(const bf16x8*)&lk[(row * 64 + 32 + g * 8) ^ sw];
        if (do0) {
          s0[c] = __builtin_amdgcn_mfma_f32_16x16x32_bf16(kf0, qf[0][0], s0[c], 0, 0, 0);
          s0[c] = __builtin_amdgcn_mfma_f32_16x16x32_bf16(kf1, qf[0][1], s0[c], 0, 0, 0);
        }
        s1[c] = __builtin_amdgcn_mfma_f32_16x16x32_bf16(kf0, qf[1][0], s1[c], 0, 0, 0);
        s1[c] = __builtin_amdgcn_mfma_f32_16x16x32_bf16(kf1, qf[1][1], s1[c], 0, 0, 0);
      }
      __builtin_amdgcn_s_setprio(0);

      // ---- online softmax (log2 units), defer-max (T13) ----
      bf16x8 pf0[2], pf1[2];
      auto softmax = [&](f32x4* s, float& mref, float& lref, f32x4* ov,
                         bf16x8* pf, bool msk, int qg) {
        float pv[16];
        #pragma unroll
        for (int c = 0; c < 4; ++c)
          #pragma unroll
          for (int e = 0; e < 4; ++e) {
            float sv = s[c][e];
            if (msk) {
              int key = kv0 + c * 16 + g * 4 + e;
              if (key > qg) sv = NEG_INF;
            }
            pv[c * 4 + e] = sv;
          }
        float t8[8];
        #pragma unroll
        for (int i = 0; i < 8; ++i) t8[i] = fmaxf(pv[i], pv[i + 8]);
        #pragma unroll
        for (int i = 0; i < 4; ++i) t8[i] = fmaxf(t8[i], t8[i + 4]);
        float tm = fmaxf(fmaxf(t8[0], t8[1]), fmaxf(t8[2], t8[3]));
        tm = fmaxf(tm, __shfl_xor(tm, 16));
        tm = fmaxf(tm, __shfl_xor(tm, 32));
        if (__any(tm > mref + 8.0f)) {   // defer-max: P bounded by 2^8
          float mn = fmaxf(mref, tm);
          float corr = exp2_fast(mref - mn);   // -inf start -> corr = 0
          lref *= corr;
          #pragma unroll
          for (int cd = 0; cd < 4; ++cd) ov[cd] *= corr;
          mref = mn;
        }
        #pragma unroll
        for (int i = 0; i < 16; ++i) pv[i] = exp2_fast(pv[i] - mref);
        float a8[8];
        #pragma unroll
        for (int i = 0; i < 8; ++i) a8[i] = pv[i] + pv[i + 8];
        #pragma unroll
        for (int i = 0; i < 4; ++i) a8[i] = a8[i] + a8[i + 4];
        float ps = (a8[0] + a8[1]) + (a8[2] + a8[3]);
        ps += __shfl_xor(ps, 16);
        ps += __shfl_xor(ps, 32);
        lref += ps;
        union { bf16x8 v; u32 w[4]; } u0, u1;
        #pragma unroll
        for (int k = 0; k < 4; ++k) {
          u0.w[k] = pk_bf16(pv[2 * k], pv[2 * k + 1]);
          u1.w[k] = pk_bf16(pv[8 + 2 * k], pv[9 + 2 * k]);
        }
        pf[0] = u0.v; pf[1] = u1.v;
      };
      if (do0) softmax(s0, mrow[0], lrow[0], o[0], pf0, pen, qg0);
      softmax(s1, mrow[1], lrow[1], o[1], pf1, last, qg0 + 64);

      // ---- PV via HW transpose reads (V shared across qb) ----
      bf16x4 tr[4][4];
      const u32 vb = (cur ? vls1 : vls0) + (u32)lane * 8;
      #pragma unroll
      for (int cd = 0; cd < 4; ++cd)
        #pragma unroll
        for (int kh = 0; kh < 4; ++kh)
          tr[cd][kh] = tr16(vb + cd * 2048 + kh * 512);
      asm volatile("s_waitcnt lgkmcnt(0)" ::: "memory");
      __builtin_amdgcn_sched_barrier(0);
      __builtin_amdgcn_s_setprio(1);
      #pragma unroll
      for (int cd = 0; cd < 4; ++cd) {
        #pragma unroll
        for (int ks = 0; ks < 2; ++ks) {
          bf16x4 lo = tr[cd][ks * 2], hi = tr[cd][ks * 2 + 1];
          bf16x8 av = { lo[0], lo[1], lo[2], lo[3], hi[0], hi[1], hi[2], hi[3] };
          if (do0) o[0][cd] = __builtin_amdgcn_mfma_f32_16x16x32_bf16(av, pf0[ks], o[0][cd], 0, 0, 0);
          o[1][cd] = __builtin_amdgcn_mfma_f32_16x16x32_bf16(av, pf1[ks], o[1][cd], 0, 0, 0);
        }
      }
      __builtin_amdgcn_s_setprio(0);

      __syncthreads();
      if (t + 2 < nt) issueKV(cur, t + 2);
      cur ^= 1;
    }

    // ---- epilogue: normalize + direct bf16 stores (no LDS) ----
    #pragma unroll
    for (int qb = 0; qb < 2; ++qb) {
      const float inv = 1.0f / lrow[qb];
      u16* op = aout + ((size_t)(b * TT) + qg0 + qb * 64) * DIM + h * HD;
      #pragma unroll
      for (int cd = 0; cd < 4; ++cd) {
        union { u16x4 v; u32 w[2]; } pk;
        pk.w[0] = pk_bf16(o[qb][cd][0] * inv, o[qb][cd][1] * inv);
        pk.w[1] = pk_bf16(o[qb][cd][2] * inv, o[qb][cd][3] * inv);
        *(u16x4*)&op[cd * 16 + g * 4] = pk.v;
      }
    }
  }
}

// ---------------- launcher ----------------
extern "C" void kernel_launch(void* const* d_in, const int* in_sizes, int n_in,
                              void* d_out, int out_size, void* d_ws, size_t ws_size,
                              hipStream_t stream) {
  const float* x    = (const float*)d_in[0];
  const float* Wqkv = (const float*)d_in[1];
  const float* bqkv = (const float*)d_in[2];
  const float* Wout = (const float*)d_in[3];
  const float* bout = (const float*)d_in[4];
  float* out = (float*)d_out;

  const int M = BB * TT;  // 8192
  u16* xb   = (u16*)d_ws;                      // [8192][1024]
  u16* wqt  = xb + (size_t)M * DIM;            // [3072][1024]
  u16* wot  = wqt + (size_t)3 * DIM * DIM;     // [1024][1024]
  u16* qkvb = wot + (size_t)DIM * DIM;         // [8192][3072]
  u16* aob  = qkvb + (size_t)M * 3 * DIM;      // [8192][1024]

  // conversions
  k_cvt<<<(M * DIM / 4 + 255) / 256, 256, 0, stream>>>(x, xb, M * DIM / 4);
  k_transpose<<<dim3(3 * DIM / 32, DIM / 32), 256, 0, stream>>>(Wqkv, wqt, DIM, 3 * DIM);
  k_transpose<<<dim3(DIM / 32, DIM / 32), 256, 0, stream>>>(Wout, wot, DIM, DIM);

  // qkv = x @ W_qkv + b_qkv  (bf16 out; Q columns pre-scaled by 0.125*log2e)
  k_gemm<1><<<dim3(3 * DIM / 128, M / 128), 256, 0, stream>>>(
      xb, wqt, bqkv, qkvb, nullptr, M, 3 * DIM, DIM, DIM, QSCALE);

  // attention
  k_attn<<<BB * NH * 8, 256, 0, stream>>>(qkvb, aob);

  // out = attn_out @ W_out + b_out  (f32 out)
  k_gemm<0><<<dim3(DIM / 128, M / 128), 256, 0, stream>>>(
      aob, wot, bout, nullptr, out, M, DIM, DIM, 0, 1.0f);
}